// Round 1
// baseline (109.399 us; speedup 1.0000x reference)
//
#include <hip/hip_runtime.h>
#include <math.h>

// Problem constants (match reference setup_inputs)
#define BB 4
#define NN 16384
#define MM 2048
#define BM (BB*MM)      // 8192  (sample queries)
#define BN (BB*NN)      // 65536 (xyz queries)

#define TGT 256         // targets per k_min block (1 KB staged -> 4 KB float4 LDS)
#define S1  64          // dir1 (smp->xyz) target splits: 64*256 = NN
#define S2  8           // dir2 (xyz->smp) target splits: 8*256  = MM

// Workspace layout (floats). Every slot plain-stored by exactly one owner
// before being read -> no init kernel. R_CNT zeroed by k_min block 0.
#define PART1OFF 0                       // [S1*BM] dir1 partial mins (incl qsq)
#define PART2OFF (S1*BM)                 // [S2*BN] dir2 partial mins (incl qsq)
#define REDOFF   (PART1OFF + S1*BM + S2*BN)
#define R_SUMS1  (REDOFF)                // [32] per-block sums of d_smp_org
#define R_MAXES  (REDOFF+32)             // [32] per-block maxes (8 blocks/batch)
#define R_SUMS2  (REDOFF+64)             // [64] per-block sums of d_org_smp
#define R_GST    (REDOFF+128)            // [32] trans partial sums
#define R_GSR    (REDOFF+160)            // [32] rot partial sums
#define R_GSC    (REDOFF+192)            // [32] cls partial sums
#define R_CNT    (REDOFF+224)            // [1]  k_reduce completion counter

typedef float f2 __attribute__((ext_vector_type(2)));

// ---- packed fp32 FMA with op_sel broadcast (VOP3P, gfx90a+) ----
// d.lo = tzw.lo*q.lo + tzw.hi ; d.hi = tzw.lo*q.hi + tzw.hi
//   (z broadcast from lo of src0, |t|^2 broadcast from hi of src2 = same pair)
__device__ __forceinline__ f2 pk_fma_zw(f2 tzw, f2 q) {
    f2 d;
    asm("v_pk_fma_f32 %0, %1, %2, %1 op_sel:[0,0,1] op_sel_hi:[0,1,1]"
        : "=v"(d) : "v"(tzw), "v"(q));
    return d;
}
// d.lo = txy.hi*q.lo + c.lo ; d.hi = txy.hi*q.hi + c.hi   (y broadcast)
__device__ __forceinline__ f2 pk_fma_hi(f2 txy, f2 q, f2 c) {
    f2 d;
    asm("v_pk_fma_f32 %0, %1, %2, %3 op_sel:[1,0,0] op_sel_hi:[1,1,1]"
        : "=v"(d) : "v"(txy), "v"(q), "v"(c));
    return d;
}
// d.lo = txy.lo*q.lo + c.lo ; d.hi = txy.lo*q.hi + c.hi   (x broadcast)
__device__ __forceinline__ f2 pk_fma_lo(f2 txy, f2 q, f2 c) {
    f2 d;
    asm("v_pk_fma_f32 %0, %1, %2, %3 op_sel:[0,0,0] op_sel_hi:[0,1,1]"
        : "=v"(d) : "v"(txy), "v"(q), "v"(c));
    return d;
}

// 512 blocks, each: 2048 queries (8/thread, held as 4 query-PAIRS) x 256
// targets in LDS. Inner loop: per 2 targets x 4 query-pairs = 24 v_pk_fma_f32
// + 8 v_min3_f32 (vs 48 fma + 8 min3 scalar) -> 1.75x fewer VALU issue slots
// if packed fp32 is full-rate on CDNA4; exactly neutral if half-rate.
// Per-target LDS float4 = (-2x,-2y,-2z,|t|^2); d' = fma chain; +|q|^2 at end.
__global__ __launch_bounds__(256) void k_min(const float* __restrict__ xyz,
                                             const float* __restrict__ smp,
                                             float* __restrict__ ws) {
    __shared__ float4 tgt[TGT];
    const int tid = threadIdx.x;
    const int bx  = blockIdx.x;
    if (bx == 0 && tid == 0) ((unsigned*)ws)[R_CNT] = 0u;  // reset fused-final counter
    const float* qptr; const float* tptr; float* outp;
    if (bx < 256) {
        // dir2: queries = xyz. per batch: 8 query-blocks x 8 target-splits.
        int b = bx >> 6, r = bx & 63, qb = r >> 3, s = r & 7;
        int gq = b * NN + qb * 2048;
        qptr = xyz + (size_t)gq * 3;
        tptr = smp + (size_t)(b * MM + s * TGT) * 3;
        outp = ws + PART2OFF + s * BN + gq;
    } else {
        // dir1: queries = smp. per batch: 1 query-block (2048=MM) x 64 splits.
        int bx2 = bx - 256;
        int b = bx2 >> 6, s = bx2 & 63;
        int gq = b * MM;
        qptr = smp + (size_t)gq * 3;
        tptr = xyz + (size_t)(b * NN + s * TGT) * 3;
        outp = ws + PART1OFF + s * BM + gq;
    }
    {   // stage: exactly one target per thread
        float x = tptr[3*tid], y = tptr[3*tid+1], z = tptr[3*tid+2];
        tgt[tid] = make_float4(-2.0f*x, -2.0f*y, -2.0f*z, x*x + y*y + z*z);
    }
    f2 qx2[4], qy2[4], qz2[4], mn2[4];
#pragma unroll
    for (int p = 0; p < 4; ++p) {
        int qa = tid + (2*p)   * 256;
        int qb = tid + (2*p+1) * 256;
        qx2[p] = (f2){qptr[3*qa],   qptr[3*qb]};
        qy2[p] = (f2){qptr[3*qa+1], qptr[3*qb+1]};
        qz2[p] = (f2){qptr[3*qa+2], qptr[3*qb+2]};
        mn2[p] = (f2){INFINITY, INFINITY};
    }
    __syncthreads();
    const f2* tg2 = (const f2*)tgt;    // [2*TGT]: {xy, zw} per target
#pragma unroll 2
    for (int j = 0; j < TGT; j += 2) {
        f2 taxy = tg2[2*j+0], tazw = tg2[2*j+1];
        f2 tbxy = tg2[2*j+2], tbzw = tg2[2*j+3];
#pragma unroll
        for (int p = 0; p < 4; ++p) {
            f2 da = pk_fma_zw(tazw, qz2[p]);
            da = pk_fma_hi(taxy, qy2[p], da);
            da = pk_fma_lo(taxy, qx2[p], da);
            f2 db = pk_fma_zw(tbzw, qz2[p]);
            db = pk_fma_hi(tbxy, qy2[p], db);
            db = pk_fma_lo(tbxy, qx2[p], db);
            mn2[p].x = fminf(mn2[p].x, fminf(da.x, db.x));  // -> v_min3_f32
            mn2[p].y = fminf(mn2[p].y, fminf(da.y, db.y));  // -> v_min3_f32
        }
    }
#pragma unroll
    for (int p = 0; p < 4; ++p) {
        int qa = tid + (2*p)   * 256;
        int qb = tid + (2*p+1) * 256;
        outp[qa] = mn2[p].x + (qx2[p].x*qx2[p].x + qy2[p].x*qy2[p].x + qz2[p].x*qz2[p].x);
        outp[qb] = mn2[p].y + (qx2[p].y*qx2[p].y + qy2[p].y*qy2[p].y + qz2[p].y*qz2[p].y);
    }
}

__device__ __forceinline__ float blockSum256(float v, volatile float* s4) {
#pragma unroll
    for (int o = 32; o > 0; o >>= 1) v += __shfl_down(v, o, 64);
    __syncthreads();
    int lane = threadIdx.x & 63, w = threadIdx.x >> 6;
    if (lane == 0) s4[w] = v;
    __syncthreads();
    return s4[0] + s4[1] + s4[2] + s4[3];
}

__device__ __forceinline__ float blockMax256(float v, volatile float* s4) {
#pragma unroll
    for (int o = 32; o > 0; o >>= 1) v = fmaxf(v, __shfl_down(v, o, 64));
    __syncthreads();
    int lane = threadIdx.x & 63, w = threadIdx.x >> 6;
    if (lane == 0) s4[w] = v;
    __syncthreads();
    return fmaxf(fmaxf(s4[0], s4[1]), fmaxf(s4[2], s4[3]));
}

// 128 blocks: [0,32) dir1 combine (1 q/thread, min over 64 splits) + sum + max;
// [32,96) dir2 combine (4 q/thread, min over 8 splits) + sum;
// [96,128) grasp/cls terms. All outputs plain per-block stores.
// The LAST block to finish (device-scope counter) runs the old k_final body:
// saves one ~2 us dispatch. GAMMA=0.5 ALPHA=0.5 BETA=1 THETA=1.
__global__ __launch_bounds__(256) void k_reduce(const float* __restrict__ gp,
                                                const float* __restrict__ gg,
                                                const float* __restrict__ cp,
                                                const float* __restrict__ cg,
                                                const float* __restrict__ temp,
                                                float* __restrict__ ws,
                                                float* __restrict__ out) {
    __shared__ float s4a[4], s4b[4], s4c[4];
    __shared__ bool amLast;
    const int bx = blockIdx.x, tid = threadIdx.x;
    if (bx < 32) {
        int q = bx * 256 + tid;
        float v = INFINITY;
#pragma unroll
        for (int sp = 0; sp < S1; ++sp) v = fminf(v, ws[PART1OFF + sp * BM + q]);
        float bs = blockSum256(v, s4a);
        float bm = blockMax256(v, s4b);
        if (tid == 0) { ws[R_SUMS1 + bx] = bs; ws[R_MAXES + bx] = bm; }
    } else if (bx < 96) {
        int i = bx - 32;
        float s = 0.0f;
#pragma unroll
        for (int k = 0; k < 4; ++k) {
            int q = i * 1024 + tid + k * 256;
            float v = INFINITY;
#pragma unroll
            for (int sp = 0; sp < S2; ++sp) v = fminf(v, ws[PART2OFF + sp * BN + q]);
            s += v;
        }
        float bs = blockSum256(s, s4a);
        if (tid == 0) ws[R_SUMS2 + i] = bs;
    } else {
        int m = (bx - 96) * 256 + tid;            // [0, 8192)
        const float* g = gp + (size_t)m * 7;
        float cxp = g[0], cyp = g[1], czp = g[2];
        float q0 = g[3], q1 = g[4], q2 = g[5], q3 = g[6];
        float invq = 1.0f / sqrtf(q0*q0 + q1*q1 + q2*q2 + q3*q3 + 1e-12f);
        const float* G = gg + (size_t)m * 16;
        float tr = G[0] + G[5] + G[10];
        float w = 0.5f * sqrtf(fmaxf(1.0f + tr, 1e-12f));
        float inv4w = 1.0f / (4.0f * w);
        float gqx = (G[9] - G[6]) * inv4w;
        float gqy = (G[2] - G[8]) * inv4w;
        float gqz = (G[4] - G[1]) * inv4w;
        float cw = cg[m];
        float dx = cxp - G[3]  + 1e-6f;
        float dy = cyp - G[7]  + 1e-6f;
        float dz = czp - G[11] + 1e-6f;
        float dist = sqrtf(dx*dx + dy*dy + dz*dz);
        float dot = (q0*w + q1*gqx + q2*gqy + q3*gqz) * invq;
        float rot = acosf(fminf(fabsf(dot), 1.0f - 1e-7f));
        float p = fminf(fmaxf(cp[m], 1e-7f), 1.0f - 1e-7f);
        float ce = cw * logf(p) + (1.0f - cw) * logf(1.0f - p);
        float s1 = blockSum256(dist * cw, s4a);
        float s2 = blockSum256(rot  * cw, s4b);
        float s3 = blockSum256(ce, s4c);
        int i = bx - 96;
        if (tid == 0) { ws[R_GST + i] = s1; ws[R_GSR + i] = s2; ws[R_GSC + i] = s3; }
    }
    // ---- fused final: last block to arrive reduces the 224 partials ----
    __threadfence();                               // release our stores (agent scope)
    if (tid == 0) {
        unsigned prev = atomicAdd((unsigned*)ws + R_CNT, 1u);
        amLast = (prev == 127u);
    }
    __syncthreads();
    if (amLast) {
        __threadfence();                           // acquire others' stores
        float a = (tid < 32) ? ws[R_SUMS1 + tid] : 0.0f;
        float f = 0.0f;
        if (tid < 4) {                             // per-batch max over its 8 block-maxes
            f = -INFINITY;
#pragma unroll
            for (int r = 0; r < 8; ++r) f = fmaxf(f, ws[R_MAXES + tid * 8 + r]);
        }
        float b = (tid < 64) ? ws[R_SUMS2 + tid] : 0.0f;
        float c = (tid < 32) ? ws[R_GST + tid] : 0.0f;
        float d = (tid < 32) ? ws[R_GSR + tid] : 0.0f;
        float e = (tid < 32) ? ws[R_GSC + tid] : 0.0f;
        float A = blockSum256(a, s4a);
        float F = blockSum256(f, s4a);
        float B = blockSum256(b, s4a);
        float C = blockSum256(c, s4a);
        float D = blockSum256(d, s4a);
        float E = blockSum256(e, s4a);
        if (tid == 0) {
            float sample = A * (1.0f / BM) + F * 0.25f + 0.5f * B * (1.0f / BN);
            float reg    = C * (1.0f / BM) + 0.5f * D * (1.0f / BM);
            float cls    = -E * (1.0f / BM);
            float t = temp[0];
            out[0] = sample + t * t + reg + cls;
        }
    }
}

extern "C" void kernel_launch(void* const* d_in, const int* in_sizes, int n_in,
                              void* d_out, int out_size, void* d_ws, size_t ws_size,
                              hipStream_t stream) {
    const float* xyz  = (const float*)d_in[0];
    const float* smp  = (const float*)d_in[1];
    const float* temp = (const float*)d_in[2];
    const float* gp   = (const float*)d_in[3];
    const float* gg   = (const float*)d_in[4];
    const float* cp   = (const float*)d_in[5];
    const float* cg   = (const float*)d_in[6];
    float* ws  = (float*)d_ws;
    float* out = (float*)d_out;

    hipLaunchKernelGGL(k_min,    dim3(512), dim3(256), 0, stream, xyz, smp, ws);
    hipLaunchKernelGGL(k_reduce, dim3(128), dim3(256), 0, stream, gp, gg, cp, cg, temp, ws, out);
}